// Round 9
// baseline (261.441 us; speedup 1.0000x reference)
//
#include <hip/hip_runtime.h>

#define B_DIM 4096
#define L_DIM 2048
#define TPB   256
#define RPB   2                  // rows processed sequentially per block
#define NW    4                  // waves per block
#define NBLK  (B_DIM / RPB)      // 2048 blocks -> full TLP
#define TAU_INV 1.0526315789473684f
#define LOG_TAU_INV 0.05129329438755058f   // ln(1/0.95)

typedef float v4f __attribute__((ext_vector_type(4)));

// Nontemporal float4 load ('nt' flag): bypasses cache allocation — avoids the
// L3 dirty-line service path left by the harness's input restore (R6: −13.5us).
__device__ __forceinline__ v4f ntload(const float* p) {
    return __builtin_nontemporal_load((const v4f*)p);
}

// R9: single-kernel fusion. Per-block partials go through device-scope
// atomicAdd into ws (1 add per block, no contention); a ticket counter elects
// the last block to fold the two sums into out[0]. Eliminates the second
// dispatch + its launch gap. RPB=2 + R7 transcendental diet retained.
// ws layout: ws[0]=trunc sum, ws[1]=bce sum, ws[2..3]=ticket counter (zeroed
// by a hipMemsetAsync graph node each call).
__global__ __launch_bounds__(TPB) void milecut_row_kernel(
    const float* __restrict__ trunc,
    const float* __restrict__ view1,
    const float* __restrict__ view2,
    const float* __restrict__ view3,
    const float* __restrict__ labels,
    float* __restrict__ acc,
    unsigned* __restrict__ cnt,
    float* __restrict__ out)
{
    const int t    = threadIdx.x;
    const int lane = t & 63;
    const int wv   = t >> 6;
    const int row0 = blockIdx.x * RPB;

    __shared__ unsigned swtot[RPB][NW];   // per-row slots: no reuse hazard
    __shared__ float    srow[RPB][NW][2]; // (esum, wtr) per row per wave
    __shared__ float    sbce[NW];

    // ---- prefetch row 0: 10 independent fully-coalesced nontemporal 16B loads ----
    size_t off = (size_t)row0 * L_DIM;
    v4f nya = ntload(labels + off + 4 * t);
    v4f nyb = ntload(labels + off + 4 * (t + 256));
    v4f nta = ntload(trunc  + off + 4 * t);
    v4f ntb = ntload(trunc  + off + 4 * (t + 256));
    v4f n1a = ntload(view1  + off + 4 * t);
    v4f n1b = ntload(view1  + off + 4 * (t + 256));
    v4f n2a = ntload(view2  + off + 4 * t);
    v4f n2b = ntload(view2  + off + 4 * (t + 256));
    v4f n3a = ntload(view3  + off + 4 * t);
    v4f n3b = ntload(view3  + off + 4 * (t + 256));

    float bce = 0.f;   // per-thread, across all RPB rows

    #pragma unroll
    for (int rr = 0; rr < RPB; ++rr) {
        // move current row into working regs
        v4f ya = nya, yb = nyb, ta = nta, tb = ntb;
        v4f u1a = n1a, u1b = n1b, u2a = n2a, u2b = n2b, u3a = n3a, u3b = n3b;
        // issue next row's loads NOW (consumed only next iteration)
        if (rr + 1 < RPB) {
            size_t o2 = (size_t)(row0 + rr + 1) * L_DIM;
            nya = ntload(labels + o2 + 4 * t);
            nyb = ntload(labels + o2 + 4 * (t + 256));
            nta = ntload(trunc  + o2 + 4 * t);
            ntb = ntload(trunc  + o2 + 4 * (t + 256));
            n1a = ntload(view1  + o2 + 4 * t);
            n1b = ntload(view1  + o2 + 4 * (t + 256));
            n2a = ntload(view2  + o2 + 4 * t);
            n2b = ntload(view2  + o2 + 4 * (t + 256));
            n3a = ntload(view3  + o2 + 4 * t);
            n3b = ntload(view3  + o2 + 4 * (t + 256));
        }

        // ---- label bitmasks; thread owns elements [4t..4t+3] and [1024+4t..] ----
        unsigned m1 = (ya.x > 0.5f ? 1u : 0u) | (ya.y > 0.5f ? 2u : 0u)
                    | (ya.z > 0.5f ? 4u : 0u) | (ya.w > 0.5f ? 8u : 0u);
        unsigned m2 = (yb.x > 0.5f ? 1u : 0u) | (yb.y > 0.5f ? 2u : 0u)
                    | (yb.z > 0.5f ? 4u : 0u) | (yb.w > 0.5f ? 8u : 0u);
        // packed per-thread sums: lo16 = group1 count, hi16 = group2 count
        unsigned pv = (unsigned)__popc(m1) | ((unsigned)__popc(m2) << 16);

        // ---- single packed inclusive wave scan (6 shfls) ----
        unsigned incl = pv;
        #pragma unroll
        for (int o = 1; o < 64; o <<= 1) {
            unsigned n = (unsigned)__shfl_up((int)incl, o, 64);
            if (lane >= o) incl += n;
        }
        if (lane == 63) swtot[rr][wv] = incl;
        __syncthreads();
        unsigned pref = 0, tot = 0;
        #pragma unroll
        for (int w = 0; w < NW; ++w) {
            unsigned x = swtot[rr][w];
            if (w < wv) pref += x;
            tot += x;
        }

        unsigned eo    = incl - pv;                       // exclusive, packed (no borrow)
        unsigned excl1 = (pref & 0xffffu) + (eo & 0xffffu);
        unsigned tot1  = tot & 0xffffu;
        unsigned excl2 = tot1 + (pref >> 16) + (eo >> 16);
        float ftotal   = (float)(tot1 + (tot >> 16));     // row label total

        // ---- fused elementwise ----
        // r = 2*cum/(k+total); e = exp(r/tau); softmax norm deferred.
        // trunc: wtr_raw = sum log(t)*e; add LOG_TAU_INV*esum at row end.
        // bce: one log of the 6-factor product per j (clamp provably inactive:
        // p in (1e-4,1-1e-4) => each log >= -9.22; product >= 1e-24 >> FLT_MIN).
        float esum = 0.f, wtr = 0.f;
        float tva[4] = {ta.x, ta.y, ta.z, ta.w};
        float tvb[4] = {tb.x, tb.y, tb.z, tb.w};
        float w1a[4] = {u1a.x, u1a.y, u1a.z, u1a.w};
        float w1b[4] = {u1b.x, u1b.y, u1b.z, u1b.w};
        float w2a[4] = {u2a.x, u2a.y, u2a.z, u2a.w};
        float w2b[4] = {u2b.x, u2b.y, u2b.z, u2b.w};
        float w3a[4] = {u3a.x, u3a.y, u3a.z, u3a.w};
        float w3b[4] = {u3b.x, u3b.y, u3b.z, u3b.w};
        const float two_tauinv = 2.0f * TAU_INV;
        #pragma unroll
        for (int j = 0; j < 4; ++j) {
            // softmax numerators (group1: elem 4t+j; group2: elem 1024+4t+j)
            unsigned c1 = excl1 + (unsigned)__popc(m1 & ((2u << j) - 1u));
            unsigned c2 = excl2 + (unsigned)__popc(m2 & ((2u << j) - 1u));
            float d1 = (float)(4 * t + j + 1) + ftotal;
            float d2 = (float)(1024 + 4 * t + j + 1) + ftotal;
            float e1 = __expf(two_tauinv * (float)c1 * __builtin_amdgcn_rcpf(d1));
            float e2 = __expf(two_tauinv * (float)c2 * __builtin_amdgcn_rcpf(d2));
            esum += e1 + e2;
            wtr  += __logf(tva[j]) * e1 + __logf(tvb[j]) * e2;
            // bce: product of the 6 selected probabilities, one log
            bool p1 = (m1 >> j) & 1u;
            bool p2 = (m2 >> j) & 1u;
            float q1 = p1 ? w1a[j] : 1.f - w1a[j];
            float q2 = p1 ? w2a[j] : 1.f - w2a[j];
            float q3 = p1 ? w3a[j] : 1.f - w3a[j];
            float q4 = p2 ? w1b[j] : 1.f - w1b[j];
            float q5 = p2 ? w2b[j] : 1.f - w2b[j];
            float q6 = p2 ? w3b[j] : 1.f - w3b[j];
            bce += __logf(((q1 * q2) * (q3 * q4)) * (q5 * q6));
        }
        wtr += LOG_TAU_INV * esum;   // fold the /tau back in, once per row-chunk

        // ---- wave-local reduce (no barrier); stash in per-(row,wave) slot ----
        #pragma unroll
        for (int o = 32; o > 0; o >>= 1) {
            esum += __shfl_down(esum, o, 64);
            wtr  += __shfl_down(wtr,  o, 64);
        }
        if (lane == 0) { srow[rr][wv][0] = esum; srow[rr][wv][1] = wtr; }
    }

    // ---- epilogue: bce wave reduce + block combine + global atomic fold ----
    #pragma unroll
    for (int o = 32; o > 0; o >>= 1) bce += __shfl_down(bce, o, 64);
    if (lane == 0) sbce[wv] = bce;
    __syncthreads();
    if (t == 0) {
        float btot = sbce[0] + sbce[1] + sbce[2] + sbce[3];
        float atr = 0.f;
        #pragma unroll
        for (int rr = 0; rr < RPB; ++rr) {
            float es = srow[rr][0][0] + srow[rr][1][0] + srow[rr][2][0] + srow[rr][3][0];
            float wt = srow[rr][0][1] + srow[rr][1][1] + srow[rr][2][1] + srow[rr][3][1];
            atr += wt / es;             // this row's sum_j log(t/tau)*q_j
        }
        // one pair of device-scope atomics per block (2048 total: no contention)
        atomicAdd(&acc[0], atr);
        atomicAdd(&acc[1], btot);
        __threadfence();                              // publish before ticket
        unsigned ticket = atomicAdd(cnt, 1u);
        if (ticket == NBLK - 1) {                     // last block: fold + write
            __threadfence();
            float St = atomicAdd(&acc[0], 0.0f);      // atomic read (bypass L1)
            float Sb = atomicAdd(&acc[1], 0.0f);
            double trunc_loss = -(double)St / (double)B_DIM;
            double vsum = -(double)Sb / ((double)B_DIM * (double)L_DIM * (double)B_DIM);
            out[0] = (float)(0.5 * trunc_loss + 0.5 * vsum);
        }
    }
}

extern "C" void kernel_launch(void* const* d_in, const int* in_sizes, int n_in,
                              void* d_out, int out_size, void* d_ws, size_t ws_size,
                              hipStream_t stream) {
    const float* trunc  = (const float*)d_in[0];
    const float* v1     = (const float*)d_in[1];
    const float* v2     = (const float*)d_in[2];
    const float* v3     = (const float*)d_in[3];
    const float* labels = (const float*)d_in[4];

    float*    acc = (float*)d_ws;          // acc[0]=trunc sum, acc[1]=bce sum
    unsigned* cnt = (unsigned*)(acc + 2);  // ticket counter

    hipMemsetAsync(d_ws, 0, 16, stream);   // graph-capture-safe memset node

    milecut_row_kernel<<<NBLK, TPB, 0, stream>>>(trunc, v1, v2, v3, labels,
                                                 acc, cnt, (float*)d_out);
}

// Round 10
// 162.214 us; speedup vs baseline: 1.6117x; 1.6117x over previous
//
#include <hip/hip_runtime.h>

#define B_DIM 4096
#define L_DIM 2048
#define TPB   256
#define RPB   2                  // rows processed sequentially per block
#define NW    4                  // waves per block
#define NBLK  (B_DIM / RPB)      // 2048 blocks -> full TLP
#define TAU_INV 1.0526315789473684f
#define LOG_TAU_INV 0.05129329438755058f   // ln(1/0.95)

typedef float v4f __attribute__((ext_vector_type(4)));

// Nontemporal float4 load ('nt' flag): bypasses cache allocation — avoids the
// L3 dirty-line service path left by the harness's input restore (R6: −13.5us).
__device__ __forceinline__ v4f ntload(const float* p) {
    return __builtin_nontemporal_load((const v4f*)p);
}

// R10 = revert to R8 (best). R9's single-kernel atomic fold regressed 100us:
// 2048 same-line cross-XCD atomicAdds + per-block threadfence serialize
// (~150cyc each). Two dispatches with per-block partials in ws is the right
// structure. RPB=2 grid (2048 blocks), R7 transcendental diet, nt loads.
// Writes per block:
//   partials[blk]        = sum over its RPB rows of (sum_j log(t/tau)*q_j)
//   partials[NBLK + blk] = raw combined bce sum over its RPB rows
__global__ __launch_bounds__(TPB) void milecut_row_kernel(
    const float* __restrict__ trunc,
    const float* __restrict__ view1,
    const float* __restrict__ view2,
    const float* __restrict__ view3,
    const float* __restrict__ labels,
    float* __restrict__ partials)
{
    const int t    = threadIdx.x;
    const int lane = t & 63;
    const int wv   = t >> 6;
    const int row0 = blockIdx.x * RPB;

    __shared__ unsigned swtot[RPB][NW];   // per-row slots: no reuse hazard
    __shared__ float    srow[RPB][NW][2]; // (esum, wtr) per row per wave
    __shared__ float    sbce[NW];

    // ---- prefetch row 0: 10 independent fully-coalesced nontemporal 16B loads ----
    size_t off = (size_t)row0 * L_DIM;
    v4f nya = ntload(labels + off + 4 * t);
    v4f nyb = ntload(labels + off + 4 * (t + 256));
    v4f nta = ntload(trunc  + off + 4 * t);
    v4f ntb = ntload(trunc  + off + 4 * (t + 256));
    v4f n1a = ntload(view1  + off + 4 * t);
    v4f n1b = ntload(view1  + off + 4 * (t + 256));
    v4f n2a = ntload(view2  + off + 4 * t);
    v4f n2b = ntload(view2  + off + 4 * (t + 256));
    v4f n3a = ntload(view3  + off + 4 * t);
    v4f n3b = ntload(view3  + off + 4 * (t + 256));

    float bce = 0.f;   // per-thread, across all RPB rows

    #pragma unroll
    for (int rr = 0; rr < RPB; ++rr) {
        // move current row into working regs
        v4f ya = nya, yb = nyb, ta = nta, tb = ntb;
        v4f u1a = n1a, u1b = n1b, u2a = n2a, u2b = n2b, u3a = n3a, u3b = n3b;
        // issue next row's loads NOW (consumed only next iteration)
        if (rr + 1 < RPB) {
            size_t o2 = (size_t)(row0 + rr + 1) * L_DIM;
            nya = ntload(labels + o2 + 4 * t);
            nyb = ntload(labels + o2 + 4 * (t + 256));
            nta = ntload(trunc  + o2 + 4 * t);
            ntb = ntload(trunc  + o2 + 4 * (t + 256));
            n1a = ntload(view1  + o2 + 4 * t);
            n1b = ntload(view1  + o2 + 4 * (t + 256));
            n2a = ntload(view2  + o2 + 4 * t);
            n2b = ntload(view2  + o2 + 4 * (t + 256));
            n3a = ntload(view3  + o2 + 4 * t);
            n3b = ntload(view3  + o2 + 4 * (t + 256));
        }

        // ---- label bitmasks; thread owns elements [4t..4t+3] and [1024+4t..] ----
        unsigned m1 = (ya.x > 0.5f ? 1u : 0u) | (ya.y > 0.5f ? 2u : 0u)
                    | (ya.z > 0.5f ? 4u : 0u) | (ya.w > 0.5f ? 8u : 0u);
        unsigned m2 = (yb.x > 0.5f ? 1u : 0u) | (yb.y > 0.5f ? 2u : 0u)
                    | (yb.z > 0.5f ? 4u : 0u) | (yb.w > 0.5f ? 8u : 0u);
        // packed per-thread sums: lo16 = group1 count, hi16 = group2 count
        unsigned pv = (unsigned)__popc(m1) | ((unsigned)__popc(m2) << 16);

        // ---- single packed inclusive wave scan (6 shfls) ----
        unsigned incl = pv;
        #pragma unroll
        for (int o = 1; o < 64; o <<= 1) {
            unsigned n = (unsigned)__shfl_up((int)incl, o, 64);
            if (lane >= o) incl += n;
        }
        if (lane == 63) swtot[rr][wv] = incl;
        __syncthreads();
        unsigned pref = 0, tot = 0;
        #pragma unroll
        for (int w = 0; w < NW; ++w) {
            unsigned x = swtot[rr][w];
            if (w < wv) pref += x;
            tot += x;
        }

        unsigned eo    = incl - pv;                       // exclusive, packed (no borrow)
        unsigned excl1 = (pref & 0xffffu) + (eo & 0xffffu);
        unsigned tot1  = tot & 0xffffu;
        unsigned excl2 = tot1 + (pref >> 16) + (eo >> 16);
        float ftotal   = (float)(tot1 + (tot >> 16));     // row label total

        // ---- fused elementwise ----
        // r = 2*cum/(k+total); e = exp(r/tau); softmax norm deferred.
        // trunc: wtr_raw = sum log(t)*e; add LOG_TAU_INV*esum at row end.
        // bce: one log of the 6-factor product per j (clamp provably inactive:
        // p in (1e-4,1-1e-4) => each log >= -9.22; product >= 1e-24 >> FLT_MIN).
        float esum = 0.f, wtr = 0.f;
        float tva[4] = {ta.x, ta.y, ta.z, ta.w};
        float tvb[4] = {tb.x, tb.y, tb.z, tb.w};
        float w1a[4] = {u1a.x, u1a.y, u1a.z, u1a.w};
        float w1b[4] = {u1b.x, u1b.y, u1b.z, u1b.w};
        float w2a[4] = {u2a.x, u2a.y, u2a.z, u2a.w};
        float w2b[4] = {u2b.x, u2b.y, u2b.z, u2b.w};
        float w3a[4] = {u3a.x, u3a.y, u3a.z, u3a.w};
        float w3b[4] = {u3b.x, u3b.y, u3b.z, u3b.w};
        const float two_tauinv = 2.0f * TAU_INV;
        #pragma unroll
        for (int j = 0; j < 4; ++j) {
            // softmax numerators (group1: elem 4t+j; group2: elem 1024+4t+j)
            unsigned c1 = excl1 + (unsigned)__popc(m1 & ((2u << j) - 1u));
            unsigned c2 = excl2 + (unsigned)__popc(m2 & ((2u << j) - 1u));
            float d1 = (float)(4 * t + j + 1) + ftotal;
            float d2 = (float)(1024 + 4 * t + j + 1) + ftotal;
            float e1 = __expf(two_tauinv * (float)c1 * __builtin_amdgcn_rcpf(d1));
            float e2 = __expf(two_tauinv * (float)c2 * __builtin_amdgcn_rcpf(d2));
            esum += e1 + e2;
            wtr  += __logf(tva[j]) * e1 + __logf(tvb[j]) * e2;
            // bce: product of the 6 selected probabilities, one log
            bool p1 = (m1 >> j) & 1u;
            bool p2 = (m2 >> j) & 1u;
            float q1 = p1 ? w1a[j] : 1.f - w1a[j];
            float q2 = p1 ? w2a[j] : 1.f - w2a[j];
            float q3 = p1 ? w3a[j] : 1.f - w3a[j];
            float q4 = p2 ? w1b[j] : 1.f - w1b[j];
            float q5 = p2 ? w2b[j] : 1.f - w2b[j];
            float q6 = p2 ? w3b[j] : 1.f - w3b[j];
            bce += __logf(((q1 * q2) * (q3 * q4)) * (q5 * q6));
        }
        wtr += LOG_TAU_INV * esum;   // fold the /tau back in, once per row-chunk

        // ---- wave-local reduce (no barrier); stash in per-(row,wave) slot ----
        #pragma unroll
        for (int o = 32; o > 0; o >>= 1) {
            esum += __shfl_down(esum, o, 64);
            wtr  += __shfl_down(wtr,  o, 64);
        }
        if (lane == 0) { srow[rr][wv][0] = esum; srow[rr][wv][1] = wtr; }
    }

    // ---- epilogue: bce wave reduce + single combine ----
    #pragma unroll
    for (int o = 32; o > 0; o >>= 1) bce += __shfl_down(bce, o, 64);
    if (lane == 0) sbce[wv] = bce;
    __syncthreads();
    if (t == 0) {
        float btot = sbce[0] + sbce[1] + sbce[2] + sbce[3];
        float atr = 0.f;
        #pragma unroll
        for (int rr = 0; rr < RPB; ++rr) {
            float es = srow[rr][0][0] + srow[rr][1][0] + srow[rr][2][0] + srow[rr][3][0];
            float wt = srow[rr][0][1] + srow[rr][1][1] + srow[rr][2][1] + srow[rr][3][1];
            atr += wt / es;             // this row's sum_j log(t/tau)*q_j
        }
        partials[blockIdx.x]        = atr;
        partials[NBLK + blockIdx.x] = btot;
    }
}

__global__ __launch_bounds__(TPB) void milecut_final_kernel(
    const float* __restrict__ partials, float* __restrict__ out)
{
    const int t = threadIdx.x;
    const float4* p4 = (const float4*)partials;   // 1024 float4 total
    float st = 0.f, sb = 0.f;
    #pragma unroll
    for (int i = 0; i < 2; ++i) {                 // trunc region: f4 0..511
        float4 a = p4[t + 256 * i];
        st += (a.x + a.y) + (a.z + a.w);
    }
    #pragma unroll
    for (int i = 2; i < 4; ++i) {                 // bce region: f4 512..1023
        float4 b = p4[t + 256 * i];
        sb += (b.x + b.y) + (b.z + b.w);
    }
    #pragma unroll
    for (int o = 32; o > 0; o >>= 1) {
        st += __shfl_down(st, o, 64);
        sb += __shfl_down(sb, o, 64);
    }
    __shared__ float s1[NW], s2[NW];
    const int lane = t & 63, wv = t >> 6;
    if (lane == 0) { s1[wv] = st; s2[wv] = sb; }
    __syncthreads();
    if (t == 0) {
        double St = 0.0, Sb = 0.0;
        #pragma unroll
        for (int w = 0; w < NW; ++w) { St += (double)s1[w]; Sb += (double)s2[w]; }
        double trunc_loss = -St / (double)B_DIM;                         // -sum(log*q)/B
        double vsum = -Sb / ((double)B_DIM * (double)L_DIM * (double)B_DIM);
        out[0] = (float)(0.5 * trunc_loss + 0.5 * vsum);
    }
}

extern "C" void kernel_launch(void* const* d_in, const int* in_sizes, int n_in,
                              void* d_out, int out_size, void* d_ws, size_t ws_size,
                              hipStream_t stream) {
    const float* trunc  = (const float*)d_in[0];
    const float* v1     = (const float*)d_in[1];
    const float* v2     = (const float*)d_in[2];
    const float* v3     = (const float*)d_in[3];
    const float* labels = (const float*)d_in[4];

    float* partials = (float*)d_ws;  // 2*NBLK*4 = 16 KB used

    milecut_row_kernel<<<NBLK, TPB, 0, stream>>>(trunc, v1, v2, v3, labels, partials);
    milecut_final_kernel<<<1, TPB, 0, stream>>>(partials, (float*)d_out);
}